// Round 10
// baseline (866.226 us; speedup 1.0000x reference)
//
#include <hip/hip_runtime.h>

#define SEQ   2048
#define BATCH 4096
#define HD    32

typedef float f32x4 __attribute__((ext_vector_type(4)));
typedef unsigned int uint2v __attribute__((ext_vector_type(2)));

// ---------------- fast device math ----------------
__device__ __forceinline__ float exp2_fast(float a) {
#if __has_builtin(__builtin_amdgcn_exp2f)
    return __builtin_amdgcn_exp2f(a);
#else
    return exp2f(a);
#endif
}

__device__ __forceinline__ float rcp_fast(float a) {
#if __has_builtin(__builtin_amdgcn_rcpf)
    return __builtin_amdgcn_rcpf(a);
#else
    return 1.0f / a;
#endif
}

// tanh(x) = sign(x) * (1 - e^{-2|x|}) / (1 + e^{-2|x|})
__device__ __forceinline__ float fast_tanh(float v) {
    float ax = fabsf(v);
    float e  = exp2_fast(ax * -2.8853900817779268f);
    float r  = (1.0f - e) * rcp_fast(1.0f + e);
    return copysignf(r, v);
}

// ---- inline-asm DPP-fused VALU ops (gfx9-class DPP16 on VOP2) ----
// v_fmac_f32_dpp D, S0, S1 : D += dpp(S0) * S1   (DPP applies to src0)
// quad_perm:[c,c,c,c] broadcasts quad-lane c's value to all 4 lanes.
#define FMAC_BC(acc, h, w, C)                                              \
    asm("v_fmac_f32_dpp %0, %1, %2 quad_perm:[" #C "," #C "," #C "," #C    \
        "] row_mask:0xf bank_mask:0xf"                                     \
        : "+v"(acc) : "v"(h), "v"(w))

#define MUL_BC(dst, h, w, C)                                               \
    asm("v_mul_f32_dpp %0, %1, %2 quad_perm:[" #C "," #C "," #C "," #C     \
        "] row_mask:0xf bank_mask:0xf"                                     \
        : "=v"(dst) : "v"(h), "v"(w))

// u = dpp(u) + u, xor-pattern reduction steps (fused add, no mov)
#define ADD_DPP_QP(u, A, B, Cc, D)                                         \
    asm("v_add_f32_dpp %0, %1, %2 quad_perm:[" #A "," #B "," #Cc "," #D    \
        "] row_mask:0xf bank_mask:0xf"                                     \
        : "=v"(u) : "v"(u), "v"(u))
#define ADD_DPP_HM(u)                                                      \
    asm("v_add_f32_dpp %0, %1, %2 row_half_mirror row_mask:0xf bank_mask:0xf" \
        : "=v"(u) : "v"(u), "v"(u))
#define ADD_DPP_M(u)                                                       \
    asm("v_add_f32_dpp %0, %1, %2 row_mirror row_mask:0xf bank_mask:0xf"   \
        : "=v"(u) : "v"(u), "v"(u))

// ds_swizzle xor-16 within 32-lane groups (HW-verified r1/r2) — fallback only.
__device__ __forceinline__ float swz_xor16(float v) {
    return __int_as_float(__builtin_amdgcn_ds_swizzle(__float_as_int(v), 0x401F));
}

// sum over {i, i^16}: permlane16_swap pair holds both values (HW-verified r4-r9).
__device__ __forceinline__ float xsum16(float v) {
#if __has_builtin(__builtin_amdgcn_permlane16_swap)
    uint2v r = __builtin_amdgcn_permlane16_swap(__float_as_uint(v), __float_as_uint(v),
                                                false, false);
    return __uint_as_float(r.x) + __uint_as_float(r.y);
#else
    return v + swz_xor16(v);
#endif
}

// sum over {i, i^32} (commutative -> both halves bit-identical). HW-verified r6-r9.
__device__ __forceinline__ float xsum32(float v) {
#if __has_builtin(__builtin_amdgcn_permlane32_swap)
    uint2v r = __builtin_amdgcn_permlane32_swap(__float_as_uint(v), __float_as_uint(v),
                                                false, false);
    return __uint_as_float(r.x) + __uint_as_float(r.y);
#else
    const int addr = (((int)(threadIdx.x & 63) ^ 32) << 2);
    const float o  = __int_as_float(
        __builtin_amdgcn_ds_bpermute(addr, __float_as_int(v)));
    return v + o;
#endif
}

// ---------------- kernel ----------------
// ONE WAVE PER BATCH ELEMENT (64 lanes/elem), 16 elements per 1024-thread
// block: 256 blocks -> 1 block/CU -> 16 waves/CU = 4 waves/SIMD.
// Lane i: row r=i&31, k-half khalf=i>>5. Per step:
//  - ds_read_b128 of chunk 4*(i&3) of the k-half: the QUAD collectively holds
//    all 16 h values; one instr touches 8 distinct 16B lines = 32 banks once,
//    8-way broadcast (cheapest possible DS read). DS per wave: 2 (was 5 in r9
//    -> 80 DS instr/CU/step, the r9 bottleneck).
//  - matvec: 16 MACs as inline-asm v_fmac_f32_dpp / v_mul_f32_dpp with
//    quad_perm broadcast of the chunk-owner lane — zero movs, zero pk
//    (r5-r9 lesson: the compiler never emitted v_pk_fma_f32; every f32x2 op
//    was 2 scalar FMAs, and every dpp helper an unfused mov).
//  - z = one permlane32_swap + add; h published by both halves (same bits).
//  - out tree: fused v_add_f32_dpp xor-steps + permlane16 cross-sum.
__global__
__attribute__((amdgpu_flat_work_group_size(1024, 1024)))
__attribute__((amdgpu_waves_per_eu(4, 4)))
void rnn_elman_kernel(
    const float* __restrict__ x, const float* __restrict__ hidden,
    const float* __restrict__ W_ih, const float* __restrict__ b_ih,
    const float* __restrict__ W_hh, const float* __restrict__ b_hh,
    const float* __restrict__ W_fc, const float* __restrict__ b_fc,
    float* __restrict__ out)
{
    __shared__ float sh[16 * 36];    // 16 elements/block (1 per wave), pad 36

    const int tid   = threadIdx.x;
    const int lane  = tid & 63;
    const int r     = lane & 31;     // owned row
    const int khalf = lane >> 5;     // k-half: [16*khalf, 16*khalf+16)
    const int wid   = tid >> 6;      // wave in block == element in block
    const int e     = __builtin_amdgcn_readfirstlane(blockIdx.x * 16 + wid);

    // ---- weights: row r, own k-half, 16 named scalars (natural order) ----
    const float* Wr = W_hh + r * HD + khalf * 16;
    const float w00 = Wr[0],  w01 = Wr[1],  w02 = Wr[2],  w03 = Wr[3];
    const float w10 = Wr[4],  w11 = Wr[5],  w12 = Wr[6],  w13 = Wr[7];
    const float w20 = Wr[8],  w21 = Wr[9],  w22 = Wr[10], w23 = Wr[11];
    const float w30 = Wr[12], w31 = Wr[13], w32 = Wr[14], w33 = Wr[15];

    // seed (x-term + bias) only on the khalf=0 copy of each row
    const float seedw = khalf ? 0.f : W_ih[r];
    const float seedb = khalf ? 0.f : (b_ih[r] + b_hh[r]);
    const float wfc   = W_fc[r];
    const float bfc   = b_fc[0];

    float* slot = sh + wid * 36;
    // each lane reads ONE 16B chunk: floats [16*khalf + 4*(lane&3), +4)
    const f32x4* rd = reinterpret_cast<const f32x4*>(slot + khalf * 16 + 4 * (lane & 3));

    // ---- init h into LDS (both halves write identical values) ----
    slot[r] = hidden[e * HD + r];
    __builtin_amdgcn_wave_barrier();
    f32x4 H = rd[0];

    // ---- x prefetch pipe (distance 4), e is wave-uniform ----
    const float* __restrict__ xe = x + e;
    float xq0 = xe[(size_t)0 * BATCH];
    float xq1 = xe[(size_t)1 * BATCH];
    float xq2 = xe[(size_t)2 * BATCH];
    float xq3 = xe[(size_t)3 * BATCH];

    #pragma unroll 4
    for (int t = 0; t < SEQ; ++t) {
        const float xv = xq0;
        xq0 = xq1; xq1 = xq2; xq2 = xq3;
        {
            int tt = t + 4; tt = tt < SEQ ? tt : SEQ - 1;   // uniform clamp
            xq3 = xe[(size_t)tt * BATCH];
        }

        const float Hx = H.x, Hy = H.y, Hz = H.z, Hw = H.w;

        // ---- matvec: 4 chains, chunk c sourced by quad-broadcast c ----
        float a0 = fmaf(xv, seedw, seedb);     // chain 0 carries the seed
        FMAC_BC(a0, Hx, w00, 0);
        FMAC_BC(a0, Hy, w01, 0);
        FMAC_BC(a0, Hz, w02, 0);
        FMAC_BC(a0, Hw, w03, 0);
        float a1; MUL_BC(a1, Hx, w10, 1);
        FMAC_BC(a1, Hy, w11, 1);
        FMAC_BC(a1, Hz, w12, 1);
        FMAC_BC(a1, Hw, w13, 1);
        float a2; MUL_BC(a2, Hx, w20, 2);
        FMAC_BC(a2, Hy, w21, 2);
        FMAC_BC(a2, Hz, w22, 2);
        FMAC_BC(a2, Hw, w23, 2);
        float a3; MUL_BC(a3, Hx, w30, 3);
        FMAC_BC(a3, Hy, w31, 3);
        FMAC_BC(a3, Hz, w32, 3);
        FMAC_BC(a3, Hw, w33, 3);
        const float pmine = (a0 + a1) + (a2 + a3);

        // ---- cross-half reduce: ONE permlane32_swap + add ----
        const float z = xsum32(pmine);          // both halves: identical bits
        const float h = fast_tanh(z);

        // ---- publish h (dual same-address write), refetch own chunk ----
        slot[r] = h;
        __builtin_amdgcn_wave_barrier();
        H = rd[0];                              // in flight under out tree

        // ---- output projection: fused add_dpp tree + permlane16 cross-sum ----
        float u = h * wfc;
        ADD_DPP_QP(u, 1, 0, 3, 2);   // xor-1
        ADD_DPP_QP(u, 2, 3, 0, 1);   // xor-2
        ADD_DPP_HM(u);               // 8-group combine
        ADD_DPP_M(u);                // 16-row total
        const float tot = xsum16(u) + bfc;      // rows 0..31 summed, all lanes

        if (lane == 0) out[(size_t)t * BATCH + e] = tot;
    }
}

// ---------------- launch ----------------
extern "C" void kernel_launch(void* const* d_in, const int* in_sizes, int n_in,
                              void* d_out, int out_size, void* d_ws, size_t ws_size,
                              hipStream_t stream) {
    const float* x    = (const float*)d_in[0];
    const float* hid  = (const float*)d_in[1];
    const float* W_ih = (const float*)d_in[2];
    const float* b_ih = (const float*)d_in[3];
    const float* W_hh = (const float*)d_in[4];
    const float* b_hh = (const float*)d_in[5];
    const float* W_fc = (const float*)d_in[6];
    const float* b_fc = (const float*)d_in[7];
    float* out = (float*)d_out;

    dim3 grid(BATCH / 16);   // 256 blocks -> 1 block/CU
    dim3 block(1024);        // 16 waves/block, 1 element/wave -> 4 waves/SIMD
    rnn_elman_kernel<<<grid, block, 0, stream>>>(x, hid, W_ih, b_ih, W_hh, b_hh,
                                                 W_fc, b_fc, out);
}

// Round 12
// 573.164 us; speedup vs baseline: 1.5113x; 1.5113x over previous
//
#include <hip/hip_runtime.h>

#define SEQ   2048
#define BATCH 4096
#define HD    32

typedef float f32x2 __attribute__((ext_vector_type(2)));
typedef float f32x4 __attribute__((ext_vector_type(4)));
typedef unsigned int uint2v __attribute__((ext_vector_type(2)));

// ---------------- fast device math ----------------
__device__ __forceinline__ float exp2_fast(float a) {
#if __has_builtin(__builtin_amdgcn_exp2f)
    return __builtin_amdgcn_exp2f(a);
#else
    return exp2f(a);
#endif
}

__device__ __forceinline__ float rcp_fast(float a) {
#if __has_builtin(__builtin_amdgcn_rcpf)
    return __builtin_amdgcn_rcpf(a);
#else
    return 1.0f / a;
#endif
}

// tanh(x) = sign(x) * (1 - e^{-2|x|}) / (1 + e^{-2|x|})  -- r0-r10 verified form
__device__ __forceinline__ float fast_tanh(float v) {
    float ax = fabsf(v);
    float e  = exp2_fast(ax * -2.8853900817779268f);
    float r  = (1.0f - e) * rcp_fast(1.0f + e);
    return copysignf(r, v);
}

// DPP exchange (old=0, bound_ctrl=0, full masks) — HW-verified r0/r2/r5.
// 0xB1 quad_perm[1,0,3,2]=xor-1 ; 0x4E quad_perm[2,3,0,1]=xor-2
template <int CTRL>
__device__ __forceinline__ float dpp_x(float v) {
    return __int_as_float(
        __builtin_amdgcn_update_dpp(0, __float_as_int(v), CTRL, 0xF, 0xF, false));
}

// ---- fused self-add DPP steps (HW-verified r10): u = dpp(u) + u
#define ADD_DPP_QP(u, A, B, Cc, D)                                          \
    asm("v_add_f32_dpp %0, %1, %2 quad_perm:[" #A "," #B "," #Cc "," #D     \
        "] row_mask:0xf bank_mask:0xf"                                      \
        : "=v"(u) : "v"(u), "v"(u))
#define ADD_DPP_HM(u)                                                       \
    asm("v_add_f32_dpp %0, %1, %2 row_half_mirror row_mask:0xf bank_mask:0xf" \
        : "=v"(u) : "v"(u), "v"(u))
#define ADD_DPP_M(u)                                                        \
    asm("v_add_f32_dpp %0, %1, %2 row_mirror row_mask:0xf bank_mask:0xf"    \
        : "=v"(u) : "v"(u), "v"(u))

// ds_swizzle xor-16 within 32-lane groups (HW-verified r1/r2) — fallback only.
__device__ __forceinline__ float swz_xor16(float v) {
    return __int_as_float(__builtin_amdgcn_ds_swizzle(__float_as_int(v), 0x401F));
}

// sum over {i, i^16} within each 32-lane group: permlane16_swap pair holds
// both values (HW-verified r4 in this exact 32-lane-group out-reduce role).
__device__ __forceinline__ float xsum16(float v) {
#if __has_builtin(__builtin_amdgcn_permlane16_swap)
    uint2v r = __builtin_amdgcn_permlane16_swap(__float_as_uint(v), __float_as_uint(v),
                                                false, false);
    return __uint_as_float(r.x) + __uint_as_float(r.y);
#else
    return v + swz_xor16(v);
#endif
}

// packed f32 fma with COMPILER-GUARANTEED semantics (llvm.fma.v2f32; the
// gfx90a+ backend selects v_pk_fma_f32 with correct modifiers). r11's
// hand-encoded op_sel asm was the prime correctness suspect -- removed.
__device__ __forceinline__ f32x2 pk_fma(f32x2 a, f32x2 b, f32x2 c) {
#if __has_builtin(__builtin_elementwise_fma)
    return __builtin_elementwise_fma(a, b, c);
#else
    return f32x2{fmaf(a.x, b.x, c.x), fmaf(a.y, b.y, c.y)};
#endif
}

// ---------------- kernel ----------------
// r5's HW-proven topology (best passing: 576 us): 32 lanes/elem, 2 elems/wave,
// 16 elems per 512-thread block, 256 blocks -> 1 block/CU, 2 waves/SIMD.
// Lane i: ks=i&3 owns k-slice [ks*8,ks*8+8); accumulates rows (i&~3)|(ks^j),
// j=0..3; 3-step DPP xor tree (r5-exact builtins) leaves row i's z in lane i.
// h broadcast via LDS (1 ds_write + 2x ds_read_b128, conflict-free broadcast).
//
// r12 deltas vs r5 (each individually verified or compiler-guaranteed):
//  - matvec: 16x pk_fma via __builtin_elementwise_fma (semantics by LLVM)
//  - out tree: fused v_add_f32_dpp self-adds (r10-verified) -- -4 movs
//  - out cross-half: permlane16_swap (r4-verified) replaces ds_swizzle --
//    removes 1 DS op + lgkmcnt stall per iteration
//  - z-tree + tanh: r5-exact verified forms (r11's unverified variants reverted)
__global__
__attribute__((amdgpu_flat_work_group_size(512, 512)))
__attribute__((amdgpu_waves_per_eu(2, 2)))
void rnn_elman_kernel(
    const float* __restrict__ x, const float* __restrict__ hidden,
    const float* __restrict__ W_ih, const float* __restrict__ b_ih,
    const float* __restrict__ W_hh, const float* __restrict__ b_hh,
    const float* __restrict__ W_fc, const float* __restrict__ b_fc,
    float* __restrict__ out)
{
    __shared__ float sh[16 * 36];    // 16 elements/block, padded stride 36

    const int tid = threadIdx.x;
    const int i   = tid & 31;        // lane within element group == owned row
    const int ks  = i & 3;           // k-slice index
    const int eb  = tid >> 5;        // element within block (0..15)
    const int e   = blockIdx.x * 16 + eb;

    // ---- weights: 4 xor-permuted rows x 8-k slice, 16 named f32x2 ----
    const int rbase = i & ~3;
    const f32x2* R0 = reinterpret_cast<const f32x2*>(W_hh + (rbase | (ks ^ 0)) * HD + ks * 8);
    const f32x2* R1 = reinterpret_cast<const f32x2*>(W_hh + (rbase | (ks ^ 1)) * HD + ks * 8);
    const f32x2* R2 = reinterpret_cast<const f32x2*>(W_hh + (rbase | (ks ^ 2)) * HD + ks * 8);
    const f32x2* R3 = reinterpret_cast<const f32x2*>(W_hh + (rbase | (ks ^ 3)) * HD + ks * 8);
    const f32x2 w0a = R0[0], w0b = R0[1], w0c = R0[2], w0d = R0[3];
    const f32x2 w1a = R1[0], w1b = R1[1], w1c = R1[2], w1d = R1[3];
    const f32x2 w2a = R2[0], w2b = R2[1], w2c = R2[2], w2d = R2[3];
    const f32x2 w3a = R3[0], w3b = R3[1], w3c = R3[2], w3d = R3[3];

    const float seedw = W_ih[i];
    const float bias  = b_ih[i] + b_hh[i];
    const float wfc   = W_fc[i];
    const float bfc   = b_fc[0];

    float* slot = sh + eb * 36;
    const f32x4* rd = reinterpret_cast<const f32x4*>(slot + ks * 8);

    // ---- init hidden state into LDS, pull my k-slice ----
    slot[i] = hidden[e * HD + i];
    __builtin_amdgcn_wave_barrier();
    f32x4 A = rd[0], B = rd[1];

    // ---- x prefetch pipe (distance 4), uniform row base ----
    const float* __restrict__ xe = x + e;
    float xq0 = xe[(size_t)0 * BATCH];
    float xq1 = xe[(size_t)1 * BATCH];
    float xq2 = xe[(size_t)2 * BATCH];
    float xq3 = xe[(size_t)3 * BATCH];

    #pragma unroll 4
    for (int t = 0; t < SEQ; ++t) {
        const float xv = xq0;
        xq0 = xq1; xq1 = xq2; xq2 = xq3;
        {
            int tt = t + 4; tt = tt < SEQ ? tt : SEQ - 1;    // uniform clamp
            const float* xr = x + (size_t)tt * BATCH;        // uniform row base
            xq3 = xr[e];
        }
        const float seed = fmaf(xv, seedw, bias);

        // ---- packed matvec: 4 rows x 4 pk_fma (32 MACs, 16 pk ops) ----
        const f32x2 h0 = __builtin_shufflevector(A, A, 0, 1);
        const f32x2 h1 = __builtin_shufflevector(A, A, 2, 3);
        const f32x2 h2 = __builtin_shufflevector(B, B, 0, 1);
        const f32x2 h3 = __builtin_shufflevector(B, B, 2, 3);
        f32x2 p0 = f32x2{seed, 0.f};
        f32x2 p1 = f32x2{0.f, 0.f};
        f32x2 p2 = f32x2{0.f, 0.f};
        f32x2 p3 = f32x2{0.f, 0.f};
        p0 = pk_fma(w0a, h0, p0); p1 = pk_fma(w1a, h0, p1);
        p2 = pk_fma(w2a, h0, p2); p3 = pk_fma(w3a, h0, p3);
        p0 = pk_fma(w0b, h1, p0); p1 = pk_fma(w1b, h1, p1);
        p2 = pk_fma(w2b, h1, p2); p3 = pk_fma(w3b, h1, p3);
        p0 = pk_fma(w0c, h2, p0); p1 = pk_fma(w1c, h2, p1);
        p2 = pk_fma(w2c, h2, p2); p3 = pk_fma(w3c, h2, p3);
        p0 = pk_fma(w0d, h3, p0); p1 = pk_fma(w1d, h3, p1);
        p2 = pk_fma(w2d, h3, p2); p3 = pk_fma(w3d, h3, p3);
        const float P0 = p0.x + p0.y;
        const float P1 = p1.x + p1.y;
        const float P2 = p2.x + p2.y;
        const float P3 = p3.x + p3.y;

        // ---- cross-slice reduce (r5-exact): lane i ends with z of row i ----
        const float q0 = P0 + dpp_x<0xB1>(P1);   // xor-1
        const float q1 = P2 + dpp_x<0xB1>(P3);   // xor-1
        const float z  = q0 + dpp_x<0x4E>(q1);   // xor-2
        const float h  = fast_tanh(z);

        // ---- publish own h, refetch k-slice (latency hides under out) ----
        slot[i] = h;
        __builtin_amdgcn_wave_barrier();
        A = rd[0]; B = rd[1];

        // ---- output projection: fused self-add DPP tree + permlane16 ----
        float u = h * wfc;
        ADD_DPP_QP(u, 1, 0, 3, 2);   // xor-1
        ADD_DPP_QP(u, 2, 3, 0, 1);   // xor-2
        ADD_DPP_HM(u);               // 8-group combine
        ADD_DPP_M(u);                // 16-row total
        const float tot = xsum16(u) + bfc;      // 32-row sum, all lanes

        if ((tid & 31) == 0) out[(size_t)t * BATCH + e] = tot;
    }
}

// ---------------- launch ----------------
extern "C" void kernel_launch(void* const* d_in, const int* in_sizes, int n_in,
                              void* d_out, int out_size, void* d_ws, size_t ws_size,
                              hipStream_t stream) {
    const float* x    = (const float*)d_in[0];
    const float* hid  = (const float*)d_in[1];
    const float* W_ih = (const float*)d_in[2];
    const float* b_ih = (const float*)d_in[3];
    const float* W_hh = (const float*)d_in[4];
    const float* b_hh = (const float*)d_in[5];
    const float* W_fc = (const float*)d_in[6];
    const float* b_fc = (const float*)d_in[7];
    float* out = (float*)d_out;

    dim3 grid(BATCH / 16);   // 256 blocks -> 1 block/CU
    dim3 block(512);         // 16 elements/block, 8 waves -> 2 waves/SIMD
    rnn_elman_kernel<<<grid, block, 0, stream>>>(x, hid, W_ih, b_ih, W_hh, b_hh,
                                                 W_fc, b_fc, out);
}